// Round 2
// baseline (1854.254 us; speedup 1.0000x reference)
//
#include <hip/hip_runtime.h>
#include <hip/hip_bf16.h>

#define B_ 128
#define S_ 512
#define C_ 16
#define E_ 100
#define CE_ 30
#define NF_ 25
#define H_ 128
#define T_ 17
#define LSTM_IN_ 175
#define G4_ 512   // 4*H

typedef __hip_bfloat16 bf16;

// ---------- helpers ----------
__device__ __forceinline__ float bf2f(unsigned short u){
  union { unsigned int i; float f; } v; v.i = ((unsigned int)u) << 16; return v.f;
}
__device__ __forceinline__ float sigm_f(float x){
  float e = __expf(-x);
  return __builtin_amdgcn_rcpf(1.0f + e);   // x<<0 -> e=inf -> rcp=0 (correct)
}
__device__ __forceinline__ float tanh_f(float x){
  x = fminf(15.0f, fmaxf(-15.0f, x));
  float e = __expf(-2.0f*x);
  return (1.0f - e) * __builtin_amdgcn_rcpf(1.0f + e);
}

// ---------- K0: word embedding gather -> feats[:, 0:100] (bf16) ----------
__global__ __launch_bounds__(256) void word_emb_kernel(const int* __restrict__ x,
    const float* __restrict__ wemb, bf16* __restrict__ feats){
  int word = blockIdx.x*2 + (threadIdx.x>>7);
  int e = threadIdx.x & 127;
  if (e < E_) feats[(size_t)word*LSTM_IN_ + e] = __float2bfloat16(wemb[(size_t)x[word]*E_ + e]);
}

// ---------- K1: char conv (width KW), relu+maxpool -> feats[:, 100+off:] ----------
template<int KW>
__global__ __launch_bounds__(256) void char_conv_kernel(const int* __restrict__ char_x,
    const float* __restrict__ cemb, const float* __restrict__ W,
    const float* __restrict__ bias, bf16* __restrict__ feats, int out_off){
  int task = blockIdx.x*256 + threadIdx.x;     // 65536*25 tasks
  int word = task / NF_;
  int fi = task - word*NF_;
  const int* cx = char_x + word*C_;
  float w[KW*CE_];
  #pragma unroll
  for (int i=0;i<KW*CE_;++i) w[i] = W[fi*CE_*KW + i];   // [fi][e][dx]
  const int NP = C_ - KW + 1;
  float acc[C_ - KW + 1];
  #pragma unroll
  for (int p=0;p<NP;++p) acc[p] = 0.0f;
  #pragma unroll
  for (int c=0;c<C_;++c){
    int ci = cx[c];
    const float* ce = cemb + ci*CE_;
    #pragma unroll
    for (int e=0;e<CE_;++e){
      float v = ce[e];
      #pragma unroll
      for (int dx=0;dx<KW;++dx){
        int p = c - dx;
        if (p >= 0 && p < NP) acc[p] = fmaf(v, w[e*KW+dx], acc[p]);
      }
    }
  }
  float m = acc[0];
  #pragma unroll
  for (int p=1;p<NP;++p) m = fmaxf(m, acc[p]);
  feats[(size_t)word*LSTM_IN_ + out_off + fi] = __float2bfloat16(fmaxf(0.0f, m + bias[fi]));
}

// ---------- K2: pre = feats @ W_ih^T + b  (both dirs), bf16 out ----------
// M=65536, N=1024 (dir*512+g), K=175.  BM=BN=128, BK=32, 8x8 per thread.
#define BM 128
#define BN 128
#define BK 32
#define LDK 36
__global__ __launch_bounds__(256) void pre_gemm_kernel(const bf16* __restrict__ feats,
    const float* __restrict__ Wf, const float* __restrict__ Wb,
    const float* __restrict__ bf_, const float* __restrict__ bb_,
    bf16* __restrict__ pre){
  __shared__ float As[BM*LDK];   // 18,432 B
  __shared__ float Bs[BN*LDK];   // 18,432 B
  int br = blockIdx.x;           // 0..511
  int bc = blockIdx.y;           // 0..7
  int dir = bc >> 2;
  int g0 = (bc & 3) * BN;
  const float* W = dir ? Wb : Wf;
  const float* bias = dir ? bb_ : bf_;
  int tid = threadIdx.x;
  int tr = tid >> 4;             // 0..15
  int tc = tid & 15;             // 0..15
  float acc[8][8];
  #pragma unroll
  for (int i=0;i<8;++i)
    #pragma unroll
    for (int j=0;j<8;++j) acc[i][j] = 0.0f;
  for (int k0 = 0; k0 < LSTM_IN_; k0 += BK){
    for (int l = tid; l < BM*BK; l += 256){
      int r = l >> 5;
      int k = l & 31;
      int kk = k0 + k;
      float av = (kk < LSTM_IN_) ? __bfloat162float(feats[(size_t)(br*BM + r)*LSTM_IN_ + kk]) : 0.0f;
      float bv = (kk < LSTM_IN_) ? W[(size_t)(g0 + r)*LSTM_IN_ + kk] : 0.0f;
      As[r*LDK + k] = av;
      Bs[r*LDK + k] = bv;
    }
    __syncthreads();
    for (int k=0;k<BK;k+=4){
      float4 a4[8], b4[8];
      #pragma unroll
      for (int i=0;i<8;++i) a4[i] = *(const float4*)&As[(tr + 16*i)*LDK + k];
      #pragma unroll
      for (int j=0;j<8;++j) b4[j] = *(const float4*)&Bs[(tc + 16*j)*LDK + k];
      #pragma unroll
      for (int i=0;i<8;++i)
        #pragma unroll
        for (int j=0;j<8;++j){
          acc[i][j] = fmaf(a4[i].x, b4[j].x, acc[i][j]);
          acc[i][j] = fmaf(a4[i].y, b4[j].y, acc[i][j]);
          acc[i][j] = fmaf(a4[i].z, b4[j].z, acc[i][j]);
          acc[i][j] = fmaf(a4[i].w, b4[j].w, acc[i][j]);
        }
    }
    __syncthreads();
  }
  #pragma unroll
  for (int i=0;i<8;++i){
    int word = br*BM + tr + 16*i;
    int b = word >> 9;
    int s = word & 511;
    #pragma unroll
    for (int j=0;j<8;++j){
      int g = g0 + tc + 16*j;
      pre[(size_t)dir*33554432 + (size_t)b*262144 + (size_t)s*512 + g] =
          __float2bfloat16(acc[i][j] + bias[g]);
    }
  }
}

// ---------- K3: LSTM recurrence, one block per (batch, dir) ----------
__global__ __launch_bounds__(512) void lstm_kernel(const bf16* __restrict__ pre,
    const float* __restrict__ Whh_f, const float* __restrict__ Whh_b,
    bf16* __restrict__ hs){
  int blk = blockIdx.x;          // 0..255
  int dir = blk & 1;
  int b = blk >> 1;
  int g = threadIdx.x;           // 0..511, thread g owns gate g
  const float* Whh = dir ? Whh_b : Whh_f;
  float w[128];
  {
    const float* Wrow = Whh + g*H_;
    #pragma unroll
    for (int k4=0;k4<32;++k4){
      float4 v = *(const float4*)&Wrow[k4*4];
      w[4*k4+0]=v.x; w[4*k4+1]=v.y; w[4*k4+2]=v.z; w[4*k4+3]=v.w;
    }
  }
  __shared__ __align__(16) float h_lds[H_];
  __shared__ float gates[G4_];
  if (g < H_) h_lds[g] = 0.0f;
  __syncthreads();
  const bf16* preB = pre + ((size_t)dir*B_ + b)*S_*G4_;
  bf16* hsB = hs + ((size_t)dir*B_ + b)*S_*H_;
  float c = 0.0f;
  int sect = g >> 7;             // 0:i 1:f 2:g 3:o  (uniform per wave)
  float nxt = __bfloat162float(preB[(size_t)(dir ? (S_-1) : 0)*G4_ + g]);
  for (int s=0;s<S_;++s){
    int idx = dir ? (S_-1-s) : s;
    float acc = nxt;
    if (s+1 < S_){
      int idx1 = dir ? (S_-2-s) : (s+1);
      nxt = __bfloat162float(preB[(size_t)idx1*G4_ + g]);   // prefetch
    }
    #pragma unroll
    for (int k4=0;k4<32;++k4){
      float4 h4 = *(const float4*)&h_lds[k4*4];   // LDS broadcast
      acc = fmaf(w[4*k4+0], h4.x, acc);
      acc = fmaf(w[4*k4+1], h4.y, acc);
      acc = fmaf(w[4*k4+2], h4.z, acc);
      acc = fmaf(w[4*k4+3], h4.w, acc);
    }
    float a = (sect == 2) ? tanh_f(acc) : sigm_f(acc);
    gates[g] = a;
    __syncthreads();              // gates visible + all h reads done
    if (g < H_){
      float iv = gates[g];
      float fv = gates[g+128];
      float gv = gates[g+256];
      float ov = gates[g+384];
      c = fmaf(fv, c, iv*gv);
      float hn = ov * tanh_f(c);
      h_lds[g] = hn;
      hsB[(size_t)idx*H_ + g] = __float2bfloat16(hn);
    }
    __syncthreads();              // new h visible
  }
}

// ---------- K4: emissions = [h_f, h_b] @ h2t_W^T + h2t_b ----------
__global__ __launch_bounds__(256) void emis_kernel(const bf16* __restrict__ hs,
    const float* __restrict__ W, const float* __restrict__ bias, float* __restrict__ em){
  int task = blockIdx.x*256 + threadIdx.x;     // 65536*17 tasks
  int word = task / T_;
  int t = task - word*T_;
  const ushort4* hf = (const ushort4*)(hs + (size_t)word*H_);
  const ushort4* hb = (const ushort4*)(hs + (size_t)(B_*S_ + word)*H_);
  const float* w0 = W + t*2*H_;
  float acc = bias[t];
  #pragma unroll
  for (int j4=0;j4<32;++j4){
    ushort4 u = hf[j4];
    float4 w4 = *(const float4*)&w0[j4*4];
    acc = fmaf(bf2f(u.x),w4.x,acc); acc = fmaf(bf2f(u.y),w4.y,acc);
    acc = fmaf(bf2f(u.z),w4.z,acc); acc = fmaf(bf2f(u.w),w4.w,acc);
  }
  #pragma unroll
  for (int j4=0;j4<32;++j4){
    ushort4 u = hb[j4];
    float4 w4 = *(const float4*)&w0[H_ + j4*4];
    acc = fmaf(bf2f(u.x),w4.x,acc); acc = fmaf(bf2f(u.y),w4.y,acc);
    acc = fmaf(bf2f(u.z),w4.z,acc); acc = fmaf(bf2f(u.w),w4.w,acc);
  }
  em[(size_t)word*T_ + t] = acc;
}

// ---------- K5a: gold-path score per batch ----------
__global__ __launch_bounds__(256) void score_kernel(const int* __restrict__ tags,
    const float* __restrict__ em, const float* __restrict__ start,
    const float* __restrict__ end_, const float* __restrict__ trans,
    float* __restrict__ score){
  int b = blockIdx.x;
  int tid = threadIdx.x;
  const int* tg = tags + b*S_;
  const float* eb = em + (size_t)b*S_*T_;
  float s = 0.0f;
  for (int t = tid; t < S_; t += 256){
    int cur = tg[t];
    s += eb[(size_t)t*T_ + cur];
    if (t > 0) s += trans[tg[t-1]*T_ + cur];
  }
  if (tid == 0) s += start[tg[0]] + end_[tg[S_-1]];
  __shared__ float red[256];
  red[tid] = s; __syncthreads();
  for (int off=128; off; off>>=1){
    if (tid < off) red[tid] += red[tid+off];
    __syncthreads();
  }
  if (tid == 0) score[b] = red[0];
}

// ---------- K5b: CRF forward (alpha) recursion -> logZ per batch ----------
__global__ __launch_bounds__(64) void crf_alpha_kernel(const float* __restrict__ em,
    const float* __restrict__ start, const float* __restrict__ end_,
    const float* __restrict__ trans, float* __restrict__ logZ){
  int b = blockIdx.x;
  int j = threadIdx.x;          // lane j owns tag j (j<17)
  __shared__ float al[T_];
  const float* eb = em + (size_t)b*S_*T_;
  float tcol[T_];
  if (j < T_){
    #pragma unroll
    for (int i=0;i<T_;++i) tcol[i] = trans[i*T_ + j];
    al[j] = start[j] + eb[j];
  }
  __syncthreads();
  float e_cur = (j < T_) ? eb[T_ + j] : 0.0f;
  for (int s=1;s<S_;++s){
    float e_nxt = (j < T_ && s+1 < S_) ? eb[(size_t)(s+1)*T_ + j] : 0.0f;
    float nv = 0.0f;
    if (j < T_){
      float av[T_];
      float m = -1e30f;
      #pragma unroll
      for (int i=0;i<T_;++i){ av[i] = al[i] + tcol[i]; m = fmaxf(m, av[i]); }
      float sum = 0.0f;
      #pragma unroll
      for (int i=0;i<T_;++i) sum += __expf(av[i]-m);
      nv = m + __logf(sum) + e_cur;
    }
    __syncthreads();
    if (j < T_) al[j] = nv;
    __syncthreads();
    e_cur = e_nxt;
  }
  if (j == 0){
    float m = -1e30f;
    float v[T_];
    #pragma unroll
    for (int i=0;i<T_;++i){ v[i] = al[i] + end_[i]; m = fmaxf(m, v[i]); }
    float sum = 0.0f;
    #pragma unroll
    for (int i=0;i<T_;++i) sum += __expf(v[i]-m);
    logZ[b] = m + __logf(sum);
  }
}

// ---------- K6: final scalar ----------
__global__ __launch_bounds__(128) void final_kernel(const float* __restrict__ logZ,
    const float* __restrict__ score, float* __restrict__ out){
  int tid = threadIdx.x;
  float v = logZ[tid] - score[tid];
  __shared__ float red[128];
  red[tid] = v; __syncthreads();
  for (int off=64; off; off>>=1){
    if (tid < off) red[tid] += red[tid+off];
    __syncthreads();
  }
  if (tid == 0) out[0] = red[0];
}

extern "C" void kernel_launch(void* const* d_in, const int* in_sizes, int n_in,
                              void* d_out, int out_size, void* d_ws, size_t ws_size,
                              hipStream_t stream) {
  const int*   x       = (const int*)  d_in[0];
  const int*   char_x  = (const int*)  d_in[1];
  const int*   tags    = (const int*)  d_in[2];
  // d_in[3] = mask: constitutively all-ones (jnp.ones) -> unused
  const float* wemb    = (const float*)d_in[4];
  const float* cemb    = (const float*)d_in[5];
  const float* c2W     = (const float*)d_in[6];
  const float* c2b     = (const float*)d_in[7];
  const float* c3W     = (const float*)d_in[8];
  const float* c3b     = (const float*)d_in[9];
  const float* c4W     = (const float*)d_in[10];
  const float* c4b     = (const float*)d_in[11];
  const float* Wih_f   = (const float*)d_in[12];
  const float* Whh_f   = (const float*)d_in[13];
  const float* b_f     = (const float*)d_in[14];
  const float* Wih_b   = (const float*)d_in[15];
  const float* Whh_b   = (const float*)d_in[16];
  const float* b_b     = (const float*)d_in[17];
  const float* h2tW    = (const float*)d_in[18];
  const float* h2tb    = (const float*)d_in[19];
  const float* crf_s   = (const float*)d_in[20];
  const float* crf_e   = (const float*)d_in[21];
  const float* crf_t   = (const float*)d_in[22];
  float* out = (float*)d_out;

  // ---- workspace layout (bytes) ----
  // feats (bf16): 65536*175*2        = 22,937,600   @ 0
  // pre   (bf16): 67,108,864*2       = 134,217,728  @ 22,937,600
  // hs    (bf16): 16,777,216*2       = 33,554,432   @ 157,155,328
  // em    (f32) : 1,114,112*4        = 4,456,448    @ 0 (overlaps dead feats)
  // score (f32) : 128*4              @ 190,709,760
  // logZ  (f32) : 128*4              @ 190,710,272
  const size_t NEEDED = 190710784ULL;
  if (ws_size < NEEDED) return;   // guard: clean numeric failure instead of GPU fault
  char* wsb = (char*)d_ws;
  bf16*  feats = (bf16*)(wsb);
  bf16*  pre   = (bf16*)(wsb + 22937600);
  bf16*  hs    = (bf16*)(wsb + 157155328);
  float* em    = (float*)(wsb);
  float* score = (float*)(wsb + 190709760);
  float* logZ  = (float*)(wsb + 190710272);

  word_emb_kernel<<<32768, 256, 0, stream>>>(x, wemb, feats);
  char_conv_kernel<2><<<6400, 256, 0, stream>>>(char_x, cemb, c2W, c2b, feats, E_);
  char_conv_kernel<3><<<6400, 256, 0, stream>>>(char_x, cemb, c3W, c3b, feats, E_ + NF_);
  char_conv_kernel<4><<<6400, 256, 0, stream>>>(char_x, cemb, c4W, c4b, feats, E_ + 2*NF_);
  pre_gemm_kernel<<<dim3(512, 8), 256, 0, stream>>>(feats, Wih_f, Wih_b, b_f, b_b, pre);
  lstm_kernel<<<256, 512, 0, stream>>>(pre, Whh_f, Whh_b, hs);
  emis_kernel<<<4352, 256, 0, stream>>>(hs, h2tW, h2tb, em);
  score_kernel<<<128, 256, 0, stream>>>(tags, em, crf_s, crf_e, crf_t, score);
  crf_alpha_kernel<<<128, 64, 0, stream>>>(em, crf_s, crf_e, crf_t, logZ);
  final_kernel<<<1, 128, 0, stream>>>(logZ, score, out);
}

// Round 6
// 1654.968 us; speedup vs baseline: 1.1204x; 1.1204x over previous
//
#include <hip/hip_runtime.h>
#include <hip/hip_bf16.h>

#define B_ 128
#define S_ 512
#define C_ 16
#define E_ 100
#define CE_ 30
#define NF_ 25
#define H_ 128
#define T_ 17
#define LSTM_IN_ 175
#define KP_ 192        // feats K padded to multiple of 32 for MFMA
#define G4_ 512        // 4*H

typedef __hip_bfloat16 bf16;
typedef short bf16x8 __attribute__((ext_vector_type(8)));
typedef float f32x4 __attribute__((ext_vector_type(4)));

// ---------- helpers (identical to round 2) ----------
__device__ __forceinline__ float bf2f(unsigned short u){
  union { unsigned int i; float f; } v; v.i = ((unsigned int)u) << 16; return v.f;
}
__device__ __forceinline__ float sigm_f(float x){
  float e = __expf(-x);
  return __builtin_amdgcn_rcpf(1.0f + e);
}
__device__ __forceinline__ float tanh_f(float x){
  x = fminf(15.0f, fmaxf(-15.0f, x));
  float e = __expf(-2.0f*x);
  return (1.0f - e) * __builtin_amdgcn_rcpf(1.0f + e);
}

// ---------- K-1: zero the K-pad columns of feats ----------
__global__ __launch_bounds__(256) void zero_pad_kernel(bf16* __restrict__ feats){
  int task = blockIdx.x*256 + threadIdx.x;      // 65536*17 = 1,114,112 exact
  int word = task / 17;
  int col = LSTM_IN_ + (task - word*17);        // 175..191
  feats[(size_t)word*KP_ + col] = __float2bfloat16(0.0f);
}

// ---------- K0: word embedding gather -> feats[:, 0:100] (round 2, stride 192) ----------
__global__ __launch_bounds__(256) void word_emb_kernel(const int* __restrict__ x,
    const float* __restrict__ wemb, bf16* __restrict__ feats){
  int word = blockIdx.x*2 + (threadIdx.x>>7);
  int e = threadIdx.x & 127;
  if (e < E_) feats[(size_t)word*KP_ + e] = __float2bfloat16(wemb[(size_t)x[word]*E_ + e]);
}

// ---------- K1: char conv (round 2 f32 version, stride 192 out) ----------
template<int KW>
__global__ __launch_bounds__(256) void char_conv_kernel(const int* __restrict__ char_x,
    const float* __restrict__ cemb, const float* __restrict__ W,
    const float* __restrict__ bias, bf16* __restrict__ feats, int out_off){
  int task = blockIdx.x*256 + threadIdx.x;     // 65536*25 tasks
  int word = task / NF_;
  int fi = task - word*NF_;
  const int* cx = char_x + word*C_;
  float w[KW*CE_];
  #pragma unroll
  for (int i=0;i<KW*CE_;++i) w[i] = W[fi*CE_*KW + i];   // [fi][e][dx]
  const int NP = C_ - KW + 1;
  float acc[C_ - KW + 1];
  #pragma unroll
  for (int p=0;p<NP;++p) acc[p] = 0.0f;
  #pragma unroll
  for (int c=0;c<C_;++c){
    int ci = cx[c];
    const float* ce = cemb + ci*CE_;
    #pragma unroll
    for (int e=0;e<CE_;++e){
      float v = ce[e];
      #pragma unroll
      for (int dx=0;dx<KW;++dx){
        int p = c - dx;
        if (p >= 0 && p < NP) acc[p] = fmaf(v, w[e*KW+dx], acc[p]);
      }
    }
  }
  float m = acc[0];
  #pragma unroll
  for (int p=1;p<NP;++p) m = fmaxf(m, acc[p]);
  feats[(size_t)word*KP_ + out_off + fi] = __float2bfloat16(fmaxf(0.0f, m + bias[fi]));
}

// ---------- W_ih f32 [512][175] (x2 dirs) -> bf16 [1024][192] zero-padded ----------
__global__ __launch_bounds__(192) void wpack_kernel(const float* __restrict__ Wf,
    const float* __restrict__ Wb, bf16* __restrict__ wpk){
  int g = blockIdx.x;            // 0..1023
  int k = threadIdx.x;           // 0..191
  float v = 0.0f;
  if (k < LSTM_IN_) v = (g < 512) ? Wf[g*LSTM_IN_ + k] : Wb[(g-512)*LSTM_IN_ + k];
  wpk[(size_t)g*KP_ + k] = __float2bfloat16(v);
}

// ---------- K2: pre = feats @ W_ih^T + b  (MFMA bf16) ----------
// M=65536 (words), per block: 128x128 tile, BK=32, K=192 (6 iters). 4 waves 2x2.
__global__ __launch_bounds__(256) void pre_gemm_mfma(const bf16* __restrict__ feats,
    const bf16* __restrict__ wpk, const float* __restrict__ bf_,
    const float* __restrict__ bb_, bf16* __restrict__ pre){
  __shared__ __align__(16) short As[4096];   // 8 subtiles x (16 rows x 32 k)
  __shared__ __align__(16) short Bs[4096];
  int br = blockIdx.x;           // 0..511
  int bc = blockIdx.y;           // 0..7
  int dir = bc >> 2;
  int g0 = (bc & 3) * 128;
  const float* bias = dir ? bb_ : bf_;
  int tid = threadIdx.x;
  int wave = tid >> 6, lane = tid & 63;
  int wr = wave >> 1, wc = wave & 1;
  const bf16* Arow = feats + (size_t)br*128*KP_;
  const bf16* Brow = wpk + (size_t)(dir*512 + g0)*KP_;
  f32x4 acc[4][4];
  #pragma unroll
  for (int i=0;i<4;++i)
    #pragma unroll
    for (int j=0;j<4;++j) acc[i][j] = (f32x4){0.f,0.f,0.f,0.f};

  for (int k0=0; k0<KP_; k0+=32){
    int4 va[2], vb[2];
    #pragma unroll
    for (int hh=0; hh<2; ++hh){
      int slot = tid + hh*256;
      int l = slot & 63;
      int row = ((slot>>6)<<4) + (l & 15);
      int kb = l >> 4;
      va[hh] = *(const int4*)(Arow + row*KP_ + k0 + kb*8);
      vb[hh] = *(const int4*)(Brow + row*KP_ + k0 + kb*8);
    }
    __syncthreads();   // prior-iteration LDS reads complete
    #pragma unroll
    for (int hh=0; hh<2; ++hh){
      int slot = tid + hh*256;
      *(int4*)&As[slot*8] = va[hh];
      *(int4*)&Bs[slot*8] = vb[hh];
    }
    __syncthreads();   // tiles visible
    bf16x8 af[4], bfr[4];
    #pragma unroll
    for (int i=0;i<4;++i) af[i]  = *(const bf16x8*)&As[(wr*4+i)*512 + lane*8];
    #pragma unroll
    for (int j=0;j<4;++j) bfr[j] = *(const bf16x8*)&Bs[(wc*4+j)*512 + lane*8];
    #pragma unroll
    for (int i=0;i<4;++i)
      #pragma unroll
      for (int j=0;j<4;++j)
        acc[i][j] = __builtin_amdgcn_mfma_f32_16x16x32_bf16(af[i], bfr[j], acc[i][j], 0, 0, 0);
  }
  // epilogue: C row = M(word), col = N(gate); bias folded here (round-2 lstm expects it)
  int row_l = (lane>>4)*4;
  int col_l = lane & 15;
  float bias_v[4];
  #pragma unroll
  for (int j=0;j<4;++j) bias_v[j] = bias[g0 + wc*64 + j*16 + col_l];
  #pragma unroll
  for (int i=0;i<4;++i){
    #pragma unroll
    for (int q=0;q<4;++q){
      int word = br*128 + wr*64 + i*16 + row_l + q;
      int bidx = word >> 9, sidx = word & 511;
      size_t base = ((size_t)(dir*B_ + bidx)*S_ + sidx)*G4_;
      #pragma unroll
      for (int j=0;j<4;++j){
        int g = g0 + wc*64 + j*16 + col_l;
        pre[base + g] = __float2bfloat16(acc[i][j][q] + bias_v[j]);
      }
    }
  }
}

// ---------- K3: LSTM recurrence (round 2 EXACT) ----------
__global__ __launch_bounds__(512) void lstm_kernel(const bf16* __restrict__ pre,
    const float* __restrict__ Whh_f, const float* __restrict__ Whh_b,
    bf16* __restrict__ hs){
  int blk = blockIdx.x;          // 0..255
  int dir = blk & 1;
  int b = blk >> 1;
  int g = threadIdx.x;           // 0..511, thread g owns gate g
  const float* Whh = dir ? Whh_b : Whh_f;
  float w[128];
  {
    const float* Wrow = Whh + g*H_;
    #pragma unroll
    for (int k4=0;k4<32;++k4){
      float4 v = *(const float4*)&Wrow[k4*4];
      w[4*k4+0]=v.x; w[4*k4+1]=v.y; w[4*k4+2]=v.z; w[4*k4+3]=v.w;
    }
  }
  __shared__ __align__(16) float h_lds[H_];
  __shared__ float gates[G4_];
  if (g < H_) h_lds[g] = 0.0f;
  __syncthreads();
  const bf16* preB = pre + ((size_t)dir*B_ + b)*S_*G4_;
  bf16* hsB = hs + ((size_t)dir*B_ + b)*S_*H_;
  float c = 0.0f;
  int sect = g >> 7;             // 0:i 1:f 2:g 3:o  (uniform per wave)
  float nxt = __bfloat162float(preB[(size_t)(dir ? (S_-1) : 0)*G4_ + g]);
  for (int s=0;s<S_;++s){
    int idx = dir ? (S_-1-s) : s;
    float acc = nxt;
    if (s+1 < S_){
      int idx1 = dir ? (S_-2-s) : (s+1);
      nxt = __bfloat162float(preB[(size_t)idx1*G4_ + g]);   // prefetch
    }
    #pragma unroll
    for (int k4=0;k4<32;++k4){
      float4 h4 = *(const float4*)&h_lds[k4*4];   // LDS broadcast
      acc = fmaf(w[4*k4+0], h4.x, acc);
      acc = fmaf(w[4*k4+1], h4.y, acc);
      acc = fmaf(w[4*k4+2], h4.z, acc);
      acc = fmaf(w[4*k4+3], h4.w, acc);
    }
    float a = (sect == 2) ? tanh_f(acc) : sigm_f(acc);
    gates[g] = a;
    __syncthreads();              // gates visible + all h reads done
    if (g < H_){
      float iv = gates[g];
      float fv = gates[g+128];
      float gv = gates[g+256];
      float ov = gates[g+384];
      c = fmaf(fv, c, iv*gv);
      float hn = ov * tanh_f(c);
      h_lds[g] = hn;
      hsB[(size_t)idx*H_ + g] = __float2bfloat16(hn);
    }
    __syncthreads();              // new h visible
  }
}

// ---------- K4: emissions (round 2 EXACT) ----------
__global__ __launch_bounds__(256) void emis_kernel(const bf16* __restrict__ hs,
    const float* __restrict__ W, const float* __restrict__ bias, float* __restrict__ em){
  int task = blockIdx.x*256 + threadIdx.x;     // 65536*17 tasks
  int word = task / T_;
  int t = task - word*T_;
  const ushort4* hf = (const ushort4*)(hs + (size_t)word*H_);
  const ushort4* hb = (const ushort4*)(hs + (size_t)(B_*S_ + word)*H_);
  const float* w0 = W + t*2*H_;
  float acc = bias[t];
  #pragma unroll
  for (int j4=0;j4<32;++j4){
    ushort4 u = hf[j4];
    float4 w4 = *(const float4*)&w0[j4*4];
    acc = fmaf(bf2f(u.x),w4.x,acc); acc = fmaf(bf2f(u.y),w4.y,acc);
    acc = fmaf(bf2f(u.z),w4.z,acc); acc = fmaf(bf2f(u.w),w4.w,acc);
  }
  #pragma unroll
  for (int j4=0;j4<32;++j4){
    ushort4 u = hb[j4];
    float4 w4 = *(const float4*)&w0[H_ + j4*4];
    acc = fmaf(bf2f(u.x),w4.x,acc); acc = fmaf(bf2f(u.y),w4.y,acc);
    acc = fmaf(bf2f(u.z),w4.z,acc); acc = fmaf(bf2f(u.w),w4.w,acc);
  }
  em[(size_t)word*T_ + t] = acc;
}

// ---------- K5a: gold-path score (round 2 EXACT) ----------
__global__ __launch_bounds__(256) void score_kernel(const int* __restrict__ tags,
    const float* __restrict__ em, const float* __restrict__ start,
    const float* __restrict__ end_, const float* __restrict__ trans,
    float* __restrict__ score){
  int b = blockIdx.x;
  int tid = threadIdx.x;
  const int* tg = tags + b*S_;
  const float* eb = em + (size_t)b*S_*T_;
  float s = 0.0f;
  for (int t = tid; t < S_; t += 256){
    int cur = tg[t];
    s += eb[(size_t)t*T_ + cur];
    if (t > 0) s += trans[tg[t-1]*T_ + cur];
  }
  if (tid == 0) s += start[tg[0]] + end_[tg[S_-1]];
  __shared__ float red[256];
  red[tid] = s; __syncthreads();
  for (int off=128; off; off>>=1){
    if (tid < off) red[tid] += red[tid+off];
    __syncthreads();
  }
  if (tid == 0) score[b] = red[0];
}

// ---------- K5b: CRF forward recursion (round 2 EXACT) ----------
__global__ __launch_bounds__(64) void crf_alpha_kernel(const float* __restrict__ em,
    const float* __restrict__ start, const float* __restrict__ end_,
    const float* __restrict__ trans, float* __restrict__ logZ){
  int b = blockIdx.x;
  int j = threadIdx.x;          // lane j owns tag j (j<17)
  __shared__ float al[T_];
  const float* eb = em + (size_t)b*S_*T_;
  float tcol[T_];
  if (j < T_){
    #pragma unroll
    for (int i=0;i<T_;++i) tcol[i] = trans[i*T_ + j];
    al[j] = start[j] + eb[j];
  }
  __syncthreads();
  float e_cur = (j < T_) ? eb[T_ + j] : 0.0f;
  for (int s=1;s<S_;++s){
    float e_nxt = (j < T_ && s+1 < S_) ? eb[(size_t)(s+1)*T_ + j] : 0.0f;
    float nv = 0.0f;
    if (j < T_){
      float av[T_];
      float m = -1e30f;
      #pragma unroll
      for (int i=0;i<T_;++i){ av[i] = al[i] + tcol[i]; m = fmaxf(m, av[i]); }
      float sum = 0.0f;
      #pragma unroll
      for (int i=0;i<T_;++i) sum += __expf(av[i]-m);
      nv = m + __logf(sum) + e_cur;
    }
    __syncthreads();
    if (j < T_) al[j] = nv;
    __syncthreads();
    e_cur = e_nxt;
  }
  if (j == 0){
    float m = -1e30f;
    float v[T_];
    #pragma unroll
    for (int i=0;i<T_;++i){ v[i] = al[i] + end_[i]; m = fmaxf(m, v[i]); }
    float sum = 0.0f;
    #pragma unroll
    for (int i=0;i<T_;++i) sum += __expf(v[i]-m);
    logZ[b] = m + __logf(sum);
  }
}

// ---------- K6: final scalar (round 2 EXACT) ----------
__global__ __launch_bounds__(128) void final_kernel(const float* __restrict__ logZ,
    const float* __restrict__ score, float* __restrict__ out){
  int tid = threadIdx.x;
  float v = logZ[tid] - score[tid];
  __shared__ float red[128];
  red[tid] = v; __syncthreads();
  for (int off=64; off; off>>=1){
    if (tid < off) red[tid] += red[tid+off];
    __syncthreads();
  }
  if (tid == 0) out[0] = red[0];
}

extern "C" void kernel_launch(void* const* d_in, const int* in_sizes, int n_in,
                              void* d_out, int out_size, void* d_ws, size_t ws_size,
                              hipStream_t stream) {
  const int*   x       = (const int*)  d_in[0];
  const int*   char_x  = (const int*)  d_in[1];
  const int*   tags    = (const int*)  d_in[2];
  // d_in[3] = mask: constitutively all-ones -> unused
  const float* wemb    = (const float*)d_in[4];
  const float* cemb    = (const float*)d_in[5];
  const float* c2W     = (const float*)d_in[6];
  const float* c2b     = (const float*)d_in[7];
  const float* c3W     = (const float*)d_in[8];
  const float* c3b     = (const float*)d_in[9];
  const float* c4W     = (const float*)d_in[10];
  const float* c4b     = (const float*)d_in[11];
  const float* Wih_f   = (const float*)d_in[12];
  const float* Whh_f   = (const float*)d_in[13];
  const float* b_f     = (const float*)d_in[14];
  const float* Wih_b   = (const float*)d_in[15];
  const float* Whh_b   = (const float*)d_in[16];
  const float* b_b     = (const float*)d_in[17];
  const float* h2tW    = (const float*)d_in[18];
  const float* h2tb    = (const float*)d_in[19];
  const float* crf_s   = (const float*)d_in[20];
  const float* crf_e   = (const float*)d_in[21];
  const float* crf_t   = (const float*)d_in[22];
  float* out = (float*)d_out;

  // ---- workspace layout (bytes) ----
  // pre   (bf16 [2][128][512][512]) 134,217,728 @ 0
  // feats (bf16 [65536][192])        25,165,824 @ 134,217,728  (end 159,383,552; dead after pre_gemm)
  // wpk   (bf16 [1024][192])            393,216 @ 159,383,552  (end 159,776,768; dead after pre_gemm)
  // hs    (bf16 [2][65536][128])     33,554,432 @ 134,217,728  (overlaps dead feats+wpk; lstm->emis)
  // em    (f32  [65536][17])          4,456,448 @ 0            (overlaps dead pre)
  // score / logZ                      @ 167,772,160 / 167,772,672
  const size_t NEEDED = 167773184ULL;
  if (ws_size < NEEDED) return;   // clean numeric failure instead of GPU fault
  char* wsb = (char*)d_ws;
  bf16*  pre   = (bf16*)(wsb);
  bf16*  feats = (bf16*)(wsb + 134217728);
  bf16*  wpk   = (bf16*)(wsb + 159383552);
  bf16*  hs    = (bf16*)(wsb + 134217728);
  float* em    = (float*)(wsb);
  float* score = (float*)(wsb + 167772160);
  float* logZ  = (float*)(wsb + 167772672);

  zero_pad_kernel<<<4352, 256, 0, stream>>>(feats);
  word_emb_kernel<<<32768, 256, 0, stream>>>(x, wemb, feats);
  char_conv_kernel<2><<<6400, 256, 0, stream>>>(char_x, cemb, c2W, c2b, feats, E_);
  char_conv_kernel<3><<<6400, 256, 0, stream>>>(char_x, cemb, c3W, c3b, feats, E_ + NF_);
  char_conv_kernel<4><<<6400, 256, 0, stream>>>(char_x, cemb, c4W, c4b, feats, E_ + 2*NF_);
  wpack_kernel<<<1024, 192, 0, stream>>>(Wih_f, Wih_b, wpk);
  pre_gemm_mfma<<<dim3(512, 8), 256, 0, stream>>>(feats, wpk, b_f, b_b, pre);
  lstm_kernel<<<256, 512, 0, stream>>>(pre, Whh_f, Whh_b, hs);
  emis_kernel<<<4352, 256, 0, stream>>>(hs, h2tW, h2tb, em);
  score_kernel<<<128, 256, 0, stream>>>(tags, em, crf_s, crf_e, crf_t, score);
  crf_alpha_kernel<<<128, 64, 0, stream>>>(em, crf_s, crf_e, crf_t, logZ);
  final_kernel<<<1, 128, 0, stream>>>(logZ, score, out);
}

// Round 7
// 1580.476 us; speedup vs baseline: 1.1732x; 1.0471x over previous
//
#include <hip/hip_runtime.h>
#include <hip/hip_bf16.h>

#define B_ 128
#define S_ 512
#define C_ 16
#define E_ 100
#define CE_ 30
#define NF_ 25
#define H_ 128
#define T_ 17
#define LSTM_IN_ 175
#define KP_ 192        // feats K padded to multiple of 32 for MFMA
#define G4_ 512        // 4*H

typedef __hip_bfloat16 bf16;
typedef short bf16x8 __attribute__((ext_vector_type(8)));
typedef float f32x4 __attribute__((ext_vector_type(4)));

// ---------- helpers ----------
__device__ __forceinline__ float bf2f(unsigned short u){
  union { unsigned int i; float f; } v; v.i = ((unsigned int)u) << 16; return v.f;
}
__device__ __forceinline__ float sigm_f(float x){
  float e = __expf(-x);
  return __builtin_amdgcn_rcpf(1.0f + e);
}
__device__ __forceinline__ float tanh_f(float x){
  x = fminf(15.0f, fmaxf(-15.0f, x));
  float e = __expf(-2.0f*x);
  return (1.0f - e) * __builtin_amdgcn_rcpf(1.0f + e);
}
__device__ __forceinline__ short bf16bits(float f){
  bf16 b = __float2bfloat16(f);
  return *(short*)&b;
}

// ---------- K-1: zero the K-pad columns of feats ----------
__global__ __launch_bounds__(256) void zero_pad_kernel(bf16* __restrict__ feats){
  int task = blockIdx.x*256 + threadIdx.x;      // 65536*17 = 1,114,112 exact
  int word = task / 17;
  int col = LSTM_IN_ + (task - word*17);        // 175..191
  feats[(size_t)word*KP_ + col] = __float2bfloat16(0.0f);
}

// ---------- K0: word embedding gather -> feats[:, 0:100] ----------
__global__ __launch_bounds__(256) void word_emb_kernel(const int* __restrict__ x,
    const float* __restrict__ wemb, bf16* __restrict__ feats){
  int word = blockIdx.x*2 + (threadIdx.x>>7);
  int e = threadIdx.x & 127;
  if (e < E_) feats[(size_t)word*KP_ + e] = __float2bfloat16(wemb[(size_t)x[word]*E_ + e]);
}

// ---------- K1: char conv (round-2 f32 version, stride-192 out) ----------
template<int KW>
__global__ __launch_bounds__(256) void char_conv_kernel(const int* __restrict__ char_x,
    const float* __restrict__ cemb, const float* __restrict__ W,
    const float* __restrict__ bias, bf16* __restrict__ feats, int out_off){
  int task = blockIdx.x*256 + threadIdx.x;     // 65536*25 tasks
  int word = task / NF_;
  int fi = task - word*NF_;
  const int* cx = char_x + word*C_;
  float w[KW*CE_];
  #pragma unroll
  for (int i=0;i<KW*CE_;++i) w[i] = W[fi*CE_*KW + i];   // [fi][e][dx]
  const int NP = C_ - KW + 1;
  float acc[C_ - KW + 1];
  #pragma unroll
  for (int p=0;p<NP;++p) acc[p] = 0.0f;
  #pragma unroll
  for (int c=0;c<C_;++c){
    int ci = cx[c];
    const float* ce = cemb + ci*CE_;
    #pragma unroll
    for (int e=0;e<CE_;++e){
      float v = ce[e];
      #pragma unroll
      for (int dx=0;dx<KW;++dx){
        int p = c - dx;
        if (p >= 0 && p < NP) acc[p] = fmaf(v, w[e*KW+dx], acc[p]);
      }
    }
  }
  float m = acc[0];
  #pragma unroll
  for (int p=1;p<NP;++p) m = fmaxf(m, acc[p]);
  feats[(size_t)word*KP_ + out_off + fi] = __float2bfloat16(fmaxf(0.0f, m + bias[fi]));
}

// ---------- W_ih f32 [512][175] (x2 dirs) -> bf16 [1024][192] zero-padded ----------
__global__ __launch_bounds__(192) void wpack_kernel(const float* __restrict__ Wf,
    const float* __restrict__ Wb, bf16* __restrict__ wpk){
  int g = blockIdx.x;            // 0..1023
  int k = threadIdx.x;           // 0..191
  float v = 0.0f;
  if (k < LSTM_IN_) v = (g < 512) ? Wf[g*LSTM_IN_ + k] : Wb[(g-512)*LSTM_IN_ + k];
  wpk[(size_t)g*KP_ + k] = __float2bfloat16(v);
}

// ---------- K2: pre = feats @ W_ih^T + b  (MFMA bf16, global_load_lds, dbuf) ----------
// 128x128 tile, BK=32, K=192 (6 steps). 4 waves 2x2. One barrier per step.
__global__ __launch_bounds__(256, 3) void pre_gemm_mfma(const bf16* __restrict__ feats,
    const bf16* __restrict__ wpk, const float* __restrict__ bf_,
    const float* __restrict__ bb_, bf16* __restrict__ pre){
  __shared__ __align__(16) short lds[16384];   // 32KB: 2 x (A 4096 + B 4096); reused as C-stage
  int br = blockIdx.x;           // 0..511
  int bc = blockIdx.y;           // 0..7
  int dir = bc >> 2;
  int g0 = (bc & 3) * 128;
  const float* bias = dir ? bb_ : bf_;
  int tid = threadIdx.x;
  int wave = tid >> 6, lane = tid & 63;
  int wr = wave >> 1, wc = wave & 1;
  int lrow = lane & 15, lkb = lane >> 4;       // lane's (row, k-chunk) within a subtile
  const bf16* Arow = feats + (size_t)br*128*KP_;
  const bf16* Brow = wpk + (size_t)(dir*512 + g0)*KP_;

  // stage one K-step (A+B tiles) into buffer at lds[bufbase..]; wave w owns subtiles 2w, 2w+1
  auto stage = [&](int bufbase, int k0){
    int s0 = wave*2, s1 = s0 + 1;
    __builtin_amdgcn_global_load_lds(
        (const __attribute__((address_space(1))) void*)(Arow + (size_t)(s0*16 + lrow)*KP_ + k0 + lkb*8),
        (__attribute__((address_space(3))) void*)&lds[bufbase + s0*512], 16, 0, 0);
    __builtin_amdgcn_global_load_lds(
        (const __attribute__((address_space(1))) void*)(Arow + (size_t)(s1*16 + lrow)*KP_ + k0 + lkb*8),
        (__attribute__((address_space(3))) void*)&lds[bufbase + s1*512], 16, 0, 0);
    __builtin_amdgcn_global_load_lds(
        (const __attribute__((address_space(1))) void*)(Brow + (size_t)(s0*16 + lrow)*KP_ + k0 + lkb*8),
        (__attribute__((address_space(3))) void*)&lds[bufbase + 4096 + s0*512], 16, 0, 0);
    __builtin_amdgcn_global_load_lds(
        (const __attribute__((address_space(1))) void*)(Brow + (size_t)(s1*16 + lrow)*KP_ + k0 + lkb*8),
        (__attribute__((address_space(3))) void*)&lds[bufbase + 4096 + s1*512], 16, 0, 0);
  };

  f32x4 acc[4][4];
  #pragma unroll
  for (int i=0;i<4;++i)
    #pragma unroll
    for (int j=0;j<4;++j) acc[i][j] = (f32x4){0.f,0.f,0.f,0.f};

  stage(0, 0);
  __syncthreads();               // barrier drains vmcnt -> tile 0 visible
  int cur = 0;
  for (int t = 0; t < 6; ++t){
    if (t < 5) stage((cur^1)*8192, (t+1)*32);    // prefetch next step (overlaps MFMA)
    const short* A  = &lds[cur*8192];
    const short* Bv = &lds[cur*8192 + 4096];
    bf16x8 af[4], bfr[4];
    #pragma unroll
    for (int i=0;i<4;++i) af[i]  = *(const bf16x8*)&A[(wr*4+i)*512 + lane*8];
    #pragma unroll
    for (int j=0;j<4;++j) bfr[j] = *(const bf16x8*)&Bv[(wc*4+j)*512 + lane*8];
    #pragma unroll
    for (int i=0;i<4;++i)
      #pragma unroll
      for (int j=0;j<4;++j)
        acc[i][j] = __builtin_amdgcn_mfma_f32_16x16x32_bf16(af[i], bfr[j], acc[i][j], 0, 0, 0);
    __syncthreads();             // staged tile landed; reads of cur done
    cur ^= 1;
  }

  // ---- epilogue: swizzled C-stage in LDS, then coalesced 16B global stores ----
  int col_l = lane & 15;
  int row_l = (lane >> 4) * 4;
  float bias_v[4];
  #pragma unroll
  for (int j=0;j<4;++j) bias_v[j] = bias[g0 + wc*64 + j*16 + col_l];
  #pragma unroll
  for (int i=0;i<4;++i){
    #pragma unroll
    for (int q=0;q<4;++q){
      int r = wr*64 + i*16 + row_l + q;        // local row (word) 0..127
      #pragma unroll
      for (int j=0;j<4;++j){
        int cbyte = (wc*64 + j*16 + col_l) * 2;
        int addr = r*256 + (cbyte ^ ((r & 7) << 4));   // XOR-swizzle within row
        *(short*)((char*)lds + addr) = bf16bits(acc[i][j][q] + bias_v[j]);
      }
    }
  }
  __syncthreads();
  int r = tid >> 1, half = tid & 1;
  int word = br*128 + r;
  int bidx = word >> 9, sidx = word & 511;
  bf16* dst = pre + ((size_t)(dir*B_ + bidx)*S_ + sidx)*G4_ + g0 + half*64;
  #pragma unroll
  for (int k=0;k<8;++k){
    int boff = (half*128 + k*16) ^ ((r & 7) << 4);
    int4 v = *(const int4*)((const char*)lds + r*256 + boff);
    *(int4*)((char*)dst + k*16) = v;
  }
}

// ---------- K3: LSTM recurrence (fp32, 4 indep FMA chains, no spill) ----------
__global__ __launch_bounds__(512, 2) void lstm_kernel(const bf16* __restrict__ pre,
    const float* __restrict__ Whh_f, const float* __restrict__ Whh_b,
    bf16* __restrict__ hs){
  int blk = blockIdx.x;          // 0..255
  int dir = blk & 1;
  int b = blk >> 1;
  int g = threadIdx.x;           // 0..511, thread g owns gate g
  const float* Whh = dir ? Whh_b : Whh_f;
  float w[128];
  {
    const float* Wrow = Whh + g*H_;
    #pragma unroll
    for (int k4=0;k4<32;++k4){
      float4 v = *(const float4*)&Wrow[k4*4];
      w[4*k4+0]=v.x; w[4*k4+1]=v.y; w[4*k4+2]=v.z; w[4*k4+3]=v.w;
    }
  }
  __shared__ __align__(16) float h_lds[H_];
  __shared__ float gates[G4_];
  if (g < H_) h_lds[g] = 0.0f;
  __syncthreads();
  const bf16* preB = pre + ((size_t)dir*B_ + b)*S_*G4_;
  bf16* hsB = hs + ((size_t)dir*B_ + b)*S_*H_;
  float c = 0.0f;
  int sect = g >> 7;             // 0:i 1:f 2:g 3:o  (uniform per wave)
  float nxt = __bfloat162float(preB[(size_t)(dir ? (S_-1) : 0)*G4_ + g]);
  for (int s=0;s<S_;++s){
    int idx = dir ? (S_-1-s) : s;
    float pr = nxt;
    if (s+1 < S_){
      int idx1 = dir ? (S_-2-s) : (s+1);
      nxt = __bfloat162float(preB[(size_t)idx1*G4_ + g]);   // prefetch
    }
    float a0=0.f, a1=0.f, a2=0.f, a3=0.f;      // 4 independent chains
    #pragma unroll
    for (int k4=0;k4<32;++k4){
      float4 h4 = *(const float4*)&h_lds[k4*4];   // LDS broadcast
      a0 = fmaf(w[4*k4+0], h4.x, a0);
      a1 = fmaf(w[4*k4+1], h4.y, a1);
      a2 = fmaf(w[4*k4+2], h4.z, a2);
      a3 = fmaf(w[4*k4+3], h4.w, a3);
    }
    float acc = pr + ((a0+a1)+(a2+a3));
    float a = (sect == 2) ? tanh_f(acc) : sigm_f(acc);
    gates[g] = a;
    __syncthreads();              // gates visible + all h reads done
    if (g < H_){
      float iv = gates[g];
      float fv = gates[g+128];
      float gv = gates[g+256];
      float ov = gates[g+384];
      c = fmaf(fv, c, iv*gv);
      float hn = ov * tanh_f(c);
      h_lds[g] = hn;
      hsB[(size_t)idx*H_ + g] = __float2bfloat16(hn);
    }
    __syncthreads();              // new h visible
  }
}

// ---------- K4: emissions ----------
__global__ __launch_bounds__(256) void emis_kernel(const bf16* __restrict__ hs,
    const float* __restrict__ W, const float* __restrict__ bias, float* __restrict__ em){
  int task = blockIdx.x*256 + threadIdx.x;     // 65536*17 tasks
  int word = task / T_;
  int t = task - word*T_;
  const ushort4* hf = (const ushort4*)(hs + (size_t)word*H_);
  const ushort4* hb = (const ushort4*)(hs + (size_t)(B_*S_ + word)*H_);
  const float* w0 = W + t*2*H_;
  float acc = bias[t];
  #pragma unroll
  for (int j4=0;j4<32;++j4){
    ushort4 u = hf[j4];
    float4 w4 = *(const float4*)&w0[j4*4];
    acc = fmaf(bf2f(u.x),w4.x,acc); acc = fmaf(bf2f(u.y),w4.y,acc);
    acc = fmaf(bf2f(u.z),w4.z,acc); acc = fmaf(bf2f(u.w),w4.w,acc);
  }
  #pragma unroll
  for (int j4=0;j4<32;++j4){
    ushort4 u = hb[j4];
    float4 w4 = *(const float4*)&w0[H_ + j4*4];
    acc = fmaf(bf2f(u.x),w4.x,acc); acc = fmaf(bf2f(u.y),w4.y,acc);
    acc = fmaf(bf2f(u.z),w4.z,acc); acc = fmaf(bf2f(u.w),w4.w,acc);
  }
  em[(size_t)word*T_ + t] = acc;
}

// ---------- K5a: gold-path score ----------
__global__ __launch_bounds__(256) void score_kernel(const int* __restrict__ tags,
    const float* __restrict__ em, const float* __restrict__ start,
    const float* __restrict__ end_, const float* __restrict__ trans,
    float* __restrict__ score){
  int b = blockIdx.x;
  int tid = threadIdx.x;
  const int* tg = tags + b*S_;
  const float* eb = em + (size_t)b*S_*T_;
  float s = 0.0f;
  for (int t = tid; t < S_; t += 256){
    int cur = tg[t];
    s += eb[(size_t)t*T_ + cur];
    if (t > 0) s += trans[tg[t-1]*T_ + cur];
  }
  if (tid == 0) s += start[tg[0]] + end_[tg[S_-1]];
  __shared__ float red[256];
  red[tid] = s; __syncthreads();
  for (int off=128; off; off>>=1){
    if (tid < off) red[tid] += red[tid+off];
    __syncthreads();
  }
  if (tid == 0) score[b] = red[0];
}

// ---------- K5b: CRF forward recursion ----------
__global__ __launch_bounds__(64) void crf_alpha_kernel(const float* __restrict__ em,
    const float* __restrict__ start, const float* __restrict__ end_,
    const float* __restrict__ trans, float* __restrict__ logZ){
  int b = blockIdx.x;
  int j = threadIdx.x;          // lane j owns tag j (j<17)
  __shared__ float al[T_];
  const float* eb = em + (size_t)b*S_*T_;
  float tcol[T_];
  if (j < T_){
    #pragma unroll
    for (int i=0;i<T_;++i) tcol[i] = trans[i*T_ + j];
    al[j] = start[j] + eb[j];
  }
  __syncthreads();
  float e_cur = (j < T_) ? eb[T_ + j] : 0.0f;
  for (int s=1;s<S_;++s){
    float e_nxt = (j < T_ && s+1 < S_) ? eb[(size_t)(s+1)*T_ + j] : 0.0f;
    float nv = 0.0f;
    if (j < T_){
      float av[T_];
      float m = -1e30f;
      #pragma unroll
      for (int i=0;i<T_;++i){ av[i] = al[i] + tcol[i]; m = fmaxf(m, av[i]); }
      float sum = 0.0f;
      #pragma unroll
      for (int i=0;i<T_;++i) sum += __expf(av[i]-m);
      nv = m + __logf(sum) + e_cur;
    }
    __syncthreads();
    if (j < T_) al[j] = nv;
    __syncthreads();
    e_cur = e_nxt;
  }
  if (j == 0){
    float m = -1e30f;
    float v[T_];
    #pragma unroll
    for (int i=0;i<T_;++i){ v[i] = al[i] + end_[i]; m = fmaxf(m, v[i]); }
    float sum = 0.0f;
    #pragma unroll
    for (int i=0;i<T_;++i) sum += __expf(v[i]-m);
    logZ[b] = m + __logf(sum);
  }
}

// ---------- K6: final scalar ----------
__global__ __launch_bounds__(128) void final_kernel(const float* __restrict__ logZ,
    const float* __restrict__ score, float* __restrict__ out){
  int tid = threadIdx.x;
  float v = logZ[tid] - score[tid];
  __shared__ float red[128];
  red[tid] = v; __syncthreads();
  for (int off=64; off; off>>=1){
    if (tid < off) red[tid] += red[tid+off];
    __syncthreads();
  }
  if (tid == 0) out[0] = red[0];
}

extern "C" void kernel_launch(void* const* d_in, const int* in_sizes, int n_in,
                              void* d_out, int out_size, void* d_ws, size_t ws_size,
                              hipStream_t stream) {
  const int*   x       = (const int*)  d_in[0];
  const int*   char_x  = (const int*)  d_in[1];
  const int*   tags    = (const int*)  d_in[2];
  // d_in[3] = mask: constitutively all-ones -> unused
  const float* wemb    = (const float*)d_in[4];
  const float* cemb    = (const float*)d_in[5];
  const float* c2W     = (const float*)d_in[6];
  const float* c2b     = (const float*)d_in[7];
  const float* c3W     = (const float*)d_in[8];
  const float* c3b     = (const float*)d_in[9];
  const float* c4W     = (const float*)d_in[10];
  const float* c4b     = (const float*)d_in[11];
  const float* Wih_f   = (const float*)d_in[12];
  const float* Whh_f   = (const float*)d_in[13];
  const float* b_f     = (const float*)d_in[14];
  const float* Wih_b   = (const float*)d_in[15];
  const float* Whh_b   = (const float*)d_in[16];
  const float* b_b     = (const float*)d_in[17];
  const float* h2tW    = (const float*)d_in[18];
  const float* h2tb    = (const float*)d_in[19];
  const float* crf_s   = (const float*)d_in[20];
  const float* crf_e   = (const float*)d_in[21];
  const float* crf_t   = (const float*)d_in[22];
  float* out = (float*)d_out;

  // ---- workspace layout (bytes) ----
  // pre   (bf16 [2][128][512][512]) 134,217,728 @ 0
  // feats (bf16 [65536][192])        25,165,824 @ 134,217,728  (dead after pre_gemm)
  // wpk   (bf16 [1024][192])            393,216 @ 159,383,552  (dead after pre_gemm)
  // hs    (bf16 [2][65536][128])     33,554,432 @ 134,217,728  (overlaps dead feats+wpk)
  // em    (f32  [65536][17])          4,456,448 @ 0            (overlaps dead pre)
  // score / logZ                      @ 167,772,160 / 167,772,672
  const size_t NEEDED = 167773184ULL;
  if (ws_size < NEEDED) return;   // clean numeric failure instead of GPU fault
  char* wsb = (char*)d_ws;
  bf16*  pre   = (bf16*)(wsb);
  bf16*  feats = (bf16*)(wsb + 134217728);
  bf16*  wpk   = (bf16*)(wsb + 159383552);
  bf16*  hs    = (bf16*)(wsb + 134217728);
  float* em    = (float*)(wsb);
  float* score = (float*)(wsb + 167772160);
  float* logZ  = (float*)(wsb + 167772672);

  zero_pad_kernel<<<4352, 256, 0, stream>>>(feats);
  word_emb_kernel<<<32768, 256, 0, stream>>>(x, wemb, feats);
  char_conv_kernel<2><<<6400, 256, 0, stream>>>(char_x, cemb, c2W, c2b, feats, E_);
  char_conv_kernel<3><<<6400, 256, 0, stream>>>(char_x, cemb, c3W, c3b, feats, E_ + NF_);
  char_conv_kernel<4><<<6400, 256, 0, stream>>>(char_x, cemb, c4W, c4b, feats, E_ + 2*NF_);
  wpack_kernel<<<1024, 192, 0, stream>>>(Wih_f, Wih_b, wpk);
  pre_gemm_mfma<<<dim3(512, 8), 256, 0, stream>>>(feats, wpk, b_f, b_b, pre);
  lstm_kernel<<<256, 512, 0, stream>>>(pre, Whh_f, Whh_b, hs);
  emis_kernel<<<4352, 256, 0, stream>>>(hs, h2tW, h2tb, em);
  score_kernel<<<128, 256, 0, stream>>>(tags, em, crf_s, crf_e, crf_t, score);
  crf_alpha_kernel<<<128, 64, 0, stream>>>(em, crf_s, crf_e, crf_t, logZ);
  final_kernel<<<1, 128, 0, stream>>>(logZ, score, out);
}